// Round 12
// baseline (106.983 us; speedup 1.0000x reference)
//
#include <hip/hip_runtime.h>
#include <cstdint>

typedef _Float16 f16x8  __attribute__((ext_vector_type(8)));
typedef float    f32x4  __attribute__((ext_vector_type(4)));

// ---------------- compile-time DCT matrix + grade filter ----------------
constexpr double kPI  = 3.14159265358979323846264338327950288;
constexpr double kLN2 = 0.69314718055994530941723212145818;
constexpr double cos_poly(double x) {            // |x| <= pi/2, Taylor
    double x2 = x * x, term = 1.0, sum = 1.0;
    for (int n = 1; n <= 13; ++n) { term *= -x2 / double((2 * n - 1) * (2 * n)); sum += term; }
    return sum;
}
constexpr double cos_idx(int a) {                // cos(a*pi/64), a mod 128
    a &= 127;
    if (a <= 32)  return  cos_poly(a * kPI / 64.0);
    if (a <= 64)  return -cos_poly((64 - a) * kPI / 64.0);
    if (a <= 96)  return -cos_poly((a - 64) * kPI / 64.0);
    return cos_poly((128 - a) * kPI / 64.0);
}
constexpr double csqrt(double v) {
    double x = 1.0;
    for (int i = 0; i < 60; ++i) x = 0.5 * (x + v / x);
    return x;
}
struct DTab { float d[1024]; };
constexpr DTab make_D() {
    DTab t{};
    const double s0 = csqrt(1.0 / 32.0);
    for (int i = 0; i < 32; ++i) {
        double sc = (i == 0) ? s0 : 0.25;        // sqrt(2/32) == 0.25 exactly
        for (int j = 0; j < 32; ++j)
            t.d[i * 32 + j] = (float)(sc * cos_idx(((2 * j + 1) * i) & 127));
    }
    return t;
}
struct FTab { float f[64]; };
constexpr FTab make_F() {                        // f(s) = ln2 * sum_g [s in band g] 2^g/n_g
    FTab t{};                                    // ln2 folded in: kernel uses log2
    const int lo[6] = {0, 11, 22, 32, 43, 54};
    const int hi[6] = {10, 21, 32, 42, 53, 62};  // s=32 in bands 2 AND 3 (fp64 boundary = 32.0)
    const int n [6] = {66, 187, 306, 286, 165, 45};
    for (int s = 0; s < 64; ++s) {
        double acc = 0.0, w = 1.0;
        for (int g = 0; g < 6; ++g) { if (s >= lo[g] && s <= hi[g]) acc += w / double(n[g]); w *= 2.0; }
        t.f[s] = (float)(acc * kLN2);
    }
    return t;
}
__device__ constexpr DTab cD = make_D();
__device__ constexpr FTab cF = make_F();

#define NP  15376   // 16 * 961 patches
#define LPB 961     // 31*31 patches per batch image
#define TP  36      // LDS T stride (fp32): same padding R9 verified

// ---------------- kernel 0: stage D fragments (fp16, 16x16x32 lane order) ---
// Frag[tile][lane][j] = D[16*tile + (lane&15)][(lane>>4)*8 + j].
// This is BOTH the A-fragment of D (stage 1) and the B-fragment of D^T
// (stage 2): B[k][n] = D^T[k][n] = D[n][k] -> identical index formula.
// (HW-verified end-to-end in R9: passed with absmax 0.0078.)
__global__ __launch_bounds__(128) void k_init(_Float16* __restrict__ dfrag) {
    const int t = threadIdx.x;                   // 128 = 2 tiles x 64 lanes
    const int tile = t >> 6, lane = t & 63;
    const int m  = 16 * tile + (lane & 15);
    const int k0 = ((lane >> 4) & 3) * 8;
    #pragma unroll
    for (int j = 0; j < 8; ++j)
        dfrag[t * 8 + j] = (_Float16)cD.d[m * 32 + k0 + j];
}

// ---------------- kernel 1: per-patch grade via 16x16x32 MFMA ----------------
// One wave = one patch, 3 channels looped (prefetched).  Z = D*P*D^T per
// channel; data path per channel is exactly R9's verified kernel.
// Layouts: A[m=lane&15][k=quad*8+j]; B[k=quad*8+j][n=lane&15];
//          C/D col=lane&15, row=quad*4+reg.
__global__ __launch_bounds__(64, 4) void k_grade(const float* __restrict__ x,
                                                 const _Float16* __restrict__ dfrag,
                                                 float* __restrict__ partial) {
    __shared__ __align__(16) float sT[32 * TP];
    __shared__ float sF[64];
    const int lane = threadIdx.x & 63;
    const int quad = lane >> 4, n = lane & 15;
    sF[lane] = cF.f[lane];

    const int task = blockIdx.x;                 // grid exact: 15376
    const int b  = task / LPB, l = task - b * LPB;
    const int ph = l / 31,     pw = l - ph * 31;

    // D fragments, resident in 8 VGPRs (L2-hot: same 2 KB for all waves)
    const f16x8* DF = (const f16x8*)dfrag;
    const f16x8 d0 = DF[lane], d1 = DF[64 + lane];

    __syncthreads();                             // single wave: waitcnt only
    // grade weights: s = 16*(mt+nt) + (quad*4 + n) + r, preloaded once
    const int sb = quad * 4 + n;
    float W[12];
    #pragma unroll
    for (int t2 = 0; t2 < 3; ++t2)
        #pragma unroll
        for (int r = 0; r < 4; ++r) W[t2 * 4 + r] = sF[sb + 16 * t2 + r];

    // P in B-operand layout: element P[quad*8+j][n (+16)]
    const float* pbase = x + (size_t)(b * 3) * 262144
                           + (size_t)(ph * 16 + quad * 8) * 512 + pw * 16 + n;
    float pv[16];
    #pragma unroll
    for (int j = 0; j < 8; ++j) { pv[j] = pbase[j * 512]; pv[8 + j] = pbase[j * 512 + 16]; }

    const f32x4 z4 = {0.f, 0.f, 0.f, 0.f};
    float gsum = 0.f;

    #pragma unroll
    for (int c = 0; c < 3; ++c) {
        f16x8 p0, p1;
        #pragma unroll
        for (int j = 0; j < 8; ++j) { p0[j] = (_Float16)pv[j]; p1[j] = (_Float16)pv[8 + j]; }
        if (c < 2) {                             // prefetch next channel behind MFMAs
            const float* nb = pbase + (size_t)(c + 1) * 262144;
            #pragma unroll
            for (int j = 0; j < 8; ++j) { pv[j] = nb[j * 512]; pv[8 + j] = nb[j * 512 + 16]; }
        }

        // stage 1: T = D * P (4 tiles of 16x16, K=32 in one MFMA each)
        f32x4 t00 = __builtin_amdgcn_mfma_f32_16x16x32_f16(d0, p0, z4, 0, 0, 0);
        f32x4 t01 = __builtin_amdgcn_mfma_f32_16x16x32_f16(d0, p1, z4, 0, 0, 0);
        f32x4 t10 = __builtin_amdgcn_mfma_f32_16x16x32_f16(d1, p0, z4, 0, 0, 0);
        f32x4 t11 = __builtin_amdgcn_mfma_f32_16x16x32_f16(d1, p1, z4, 0, 0, 0);

        // C-layout -> LDS [row][col] (pad 36)
        #pragma unroll
        for (int r = 0; r < 4; ++r) {
            sT[(quad * 4 + r) * TP + n]           = t00[r];
            sT[(quad * 4 + r) * TP + 16 + n]      = t01[r];
            sT[(16 + quad * 4 + r) * TP + n]      = t10[r];
            sT[(16 + quad * 4 + r) * TP + 16 + n] = t11[r];
        }
        __syncthreads();

        // read T in A-operand layout (m = n + 16*mt, k = quad*8+j), cvt fp16
        f16x8 a0, a1;
        {
            const float* rp = &sT[n * TP + quad * 8];
            const float4 x0 = *(const float4*)(rp);
            const float4 x1 = *(const float4*)(rp + 4);
            const float4 x2 = *(const float4*)(rp + 16 * TP);
            const float4 x3 = *(const float4*)(rp + 16 * TP + 4);
            a0[0]=(_Float16)x0.x; a0[1]=(_Float16)x0.y; a0[2]=(_Float16)x0.z; a0[3]=(_Float16)x0.w;
            a0[4]=(_Float16)x1.x; a0[5]=(_Float16)x1.y; a0[6]=(_Float16)x1.z; a0[7]=(_Float16)x1.w;
            a1[0]=(_Float16)x2.x; a1[1]=(_Float16)x2.y; a1[2]=(_Float16)x2.z; a1[3]=(_Float16)x2.w;
            a1[4]=(_Float16)x3.x; a1[5]=(_Float16)x3.y; a1[6]=(_Float16)x3.z; a1[7]=(_Float16)x3.w;
        }
        __syncthreads();                         // reads drained before next write

        // stage 2: Z = T * D^T (B-frag of D^T == D fragments)
        f32x4 q00 = __builtin_amdgcn_mfma_f32_16x16x32_f16(a0, d0, z4, 0, 0, 0);
        f32x4 q01 = __builtin_amdgcn_mfma_f32_16x16x32_f16(a0, d1, z4, 0, 0, 0);
        f32x4 q10 = __builtin_amdgcn_mfma_f32_16x16x32_f16(a1, d0, z4, 0, 0, 0);
        f32x4 q11 = __builtin_amdgcn_mfma_f32_16x16x32_f16(a1, d1, z4, 0, 0, 0);

        #pragma unroll
        for (int r = 0; r < 4; ++r) {
            gsum = fmaf(__log2f(fabsf(q00[r]) + 1.f), W[r],     gsum);
            gsum = fmaf(__log2f(fabsf(q01[r]) + 1.f), W[4 + r], gsum);
            gsum = fmaf(__log2f(fabsf(q10[r]) + 1.f), W[4 + r], gsum);
            gsum = fmaf(__log2f(fabsf(q11[r]) + 1.f), W[8 + r], gsum);
        }
    }
    #pragma unroll
    for (int off = 32; off > 0; off >>= 1) gsum += __shfl_down(gsum, off, 64);
    if (lane == 0) partial[task] = gsum;
}

// ---------------- kernel 2: fused select + gather ----------------
// Block b: top-2/bottom-2 over its 961 grades (u64 key = grade_bits<<32 | idx
// matches stable-argsort tie semantics), then copies the 4 selected raw
// patches (level_y == patches: LEVEL_FILT all-ones, D orthonormal).
__global__ __launch_bounds__(256) void k_selgather(const float* __restrict__ partial,
                                                   const float* __restrict__ x,
                                                   float* __restrict__ out) {
    __shared__ unsigned long long smx1[256], smx2[256], smn1[256], smn2[256];
    __shared__ int ssel[4];
    const int b = blockIdx.x, tid = threadIdx.x;
    unsigned long long mx1 = 0, mx2 = 0, mn1 = ~0ULL, mn2 = ~0ULL;
    for (int l = tid; l < LPB; l += 256) {
        unsigned int bits = __float_as_uint(partial[b * LPB + l]);
        unsigned long long k = ((unsigned long long)bits << 32) | (unsigned int)l;
        if (k > mx1) { mx2 = mx1; mx1 = k; } else if (k > mx2) { mx2 = k; }
        if (k < mn1) { mn2 = mn1; mn1 = k; } else if (k < mn2) { mn2 = k; }
    }
    smx1[tid] = mx1; smx2[tid] = mx2; smn1[tid] = mn1; smn2[tid] = mn2;
    for (int off = 128; off > 0; off >>= 1) {
        __syncthreads();
        if (tid < off) {
            unsigned long long a1 = smx1[tid], a2 = smx2[tid], b1 = smx1[tid + off], b2 = smx2[tid + off];
            unsigned long long lo = a1 < b1 ? a1 : b1, hi = a1 < b1 ? b1 : a1;
            unsigned long long c2 = a2 > b2 ? a2 : b2;
            smx1[tid] = hi; smx2[tid] = lo > c2 ? lo : c2;
            a1 = smn1[tid]; a2 = smn2[tid]; b1 = smn1[tid + off]; b2 = smn2[tid + off];
            lo = a1 < b1 ? a1 : b1; hi = a1 < b1 ? b1 : a1;
            c2 = a2 < b2 ? a2 : b2;
            smn1[tid] = lo; smn2[tid] = hi < c2 ? hi : c2;
        }
    }
    __syncthreads();
    if (tid == 0) {
        ssel[0] = (int)(smn1[0] & 0xffffffffu);  // x_minmin
        ssel[1] = (int)(smx1[0] & 0xffffffffu);  // x_maxmax
        ssel[2] = (int)(smn2[0] & 0xffffffffu);  // x_minmin1
        ssel[3] = (int)(smx2[0] & 0xffffffffu);  // x_maxmax1
    }
    __syncthreads();

    // gather: 4 outputs x 3 ch x 32 x 32 floats = 3072 float4 per batch
    #pragma unroll
    for (int it = 0; it < 12; ++it) {
        const int q  = it * 256 + tid;           // [0, 3072)
        const int o  = q / 768;
        const int r2 = q - o * 768;
        const int c  = r2 >> 8;
        const int p  = r2 & 255;
        const int i  = p >> 3, j4 = p & 7;
        const int l  = ssel[o];
        const int r0 = (l / 31) * 16, c0 = (l - (l / 31) * 31) * 16;
        const float4 v = *(const float4*)(x + ((size_t)(b * 3 + c) * 512 + r0 + i) * 512 + c0 + 4 * j4);
        *(float4*)(out + (size_t)o * 49152 + b * 3072 + c * 1024 + i * 32 + 4 * j4) = v;
    }
}

extern "C" void kernel_launch(void* const* d_in, const int* in_sizes, int n_in,
                              void* d_out, int out_size, void* d_ws, size_t ws_size,
                              hipStream_t stream) {
    const float* x = (const float*)d_in[0];
    float* out     = (float*)d_out;
    float* partial = (float*)d_ws;                       // NP floats (61504 B)
    _Float16* dfrag = (_Float16*)((char*)d_ws + 61504);  // 1024 halfs, 16B-aligned
    k_init     <<<1,  128, 0, stream>>>(dfrag);
    k_grade    <<<NP,  64, 0, stream>>>(x, dfrag, partial);
    k_selgather<<<16, 256, 0, stream>>>(partial, x, out);
}